// Round 1
// baseline (302.062 us; speedup 1.0000x reference)
//
#include <hip/hip_runtime.h>
#include <math.h>

// Problem constants (B=1 fixed by reference)
#define NP 9216          // S*S spatial positions
#define DC 256           // channels
#define DN (DC * NP)
#define NT 36            // 9216 / 256 tiles per dim
#define CH64 (NP * 64)   // halves per 64-wide k-chunk of a plane

#define FEPS 2.220446049250313e-16f

typedef __attribute__((ext_vector_type(8))) _Float16 half8v;
typedef __attribute__((ext_vector_type(4))) float   float4v;

union HU { _Float16 h; unsigned short u; };
__device__ __forceinline__ unsigned short f2h(float f) { HU x; x.h = (_Float16)f; return x.u; }
__device__ __forceinline__ float h2f(unsigned short s) { HU x; x.u = s; return (float)x.h; }

// Plane layout (k-major, 64-wide chunks): half index off(n,k) = (k>>6)*CH64 + n*64 + (k&63)
// -> a 256-row x 64-k tile is one contiguous 32 KB block: ideal for global_load_lds.
//
// Split: H = fp16(s), R = fp16(s - H) at NATURAL scale. Then
//   s_x . s_y  =  Hx.Hy + Hx.Ry + Rx.Hy   (+ Rx.Ry, dropped: <= 2^-24 rel)
// i.e. ONE pure GEMM with extended K = 768 realized by swapping plane base
// pointers per K-tile:  A = [H|H|R],  B = [H|R|H].  No VALU fixup at all.

// ---------------- Kernel 1: fused normalize + fp16 H/R split ----------------
__global__ __launch_bounds__(256) void kprep(
    const float* __restrict__ X, const float* __restrict__ Y,
    float* __restrict__ Xf_out,
    unsigned short* __restrict__ XH, unsigned short* __restrict__ XR,
    unsigned short* __restrict__ YH, unsigned short* __restrict__ YR,
    float* __restrict__ lacc)
{
    __shared__ float tile[64 * 257];   // (n, d) at n*257+d
    __shared__ float psum[4][64];
    __shared__ float invs[64];

    const int t = threadIdx.x;
    const bool isX = (blockIdx.y == 0);
    const float* src = isX ? X : Y;
    unsigned* hT = (unsigned*)(isX ? XH : YH);
    unsigned* rT = (unsigned*)(isX ? XR : YR);
    const int n0 = blockIdx.x * 64;

    if (blockIdx.x == 0 && blockIdx.y == 0 && t == 0) *lacc = 0.0f;

    const int lane = t & 63;
    const int w    = t >> 6;      // wave id -> owns d-range [w*64, w*64+64)

    #pragma unroll 8
    for (int i = 0; i < 64; ++i) {
        int d = w * 64 + i;
        tile[lane * 257 + d] = src[(size_t)d * NP + n0 + lane];
    }
    float s = 0.0f;
    #pragma unroll 8
    for (int i = 0; i < 64; ++i) {
        float v = tile[lane * 257 + w * 64 + i];
        s = fmaf(v, v, s);
    }
    psum[w][lane] = s;
    __syncthreads();
    if (t < 64) {
        float tot = psum[0][t] + psum[1][t] + psum[2][t] + psum[3][t];
        invs[t] = 1.0f / (sqrtf(tot) + FEPS);
    }
    __syncthreads();

    // plane writes, 64-wide k-chunk layout; coalesced uints.
    #pragma unroll 8
    for (int rep = 0; rep < 32; ++rep) {
        int idx = rep * 256 + t;
        int n = idx >> 7;          // 0..63
        int u = idx & 127;         // uint within row (2 halves each)
        int c = u >> 5;            // chunk 0..3
        int j = u & 31;            // uint within chunk
        int d = c * 64 + 2 * j;
        float inv = invs[n] * 256.0f;
        float s0 = tile[n * 257 + d] * inv;
        float s1 = tile[n * 257 + d + 1] * inv;
        unsigned short h0 = f2h(s0), h1 = f2h(s1);
        unsigned short r0 = f2h(s0 - h2f(h0));
        unsigned short r1 = f2h(s1 - h2f(h1));
        size_t uo = (size_t)c * (CH64 / 2) + (size_t)(n0 + n) * 32 + j;
        hT[uo] = (unsigned)h0 | ((unsigned)h1 << 16);
        rT[uo] = (unsigned)r0 | ((unsigned)r1 << 16);
    }

    // exact fp32 Xf output ([d][n], coalesced over n)
    if (isX) {
        const float inv = invs[lane];
        #pragma unroll 8
        for (int i = 0; i < 64; ++i) {
            int d = w * 64 + i;
            Xf_out[(size_t)d * NP + n0 + lane] = tile[lane * 257 + d] * inv;
        }
    }
}

// ---------------- Kernel 2: 256^2-tile 8-phase MFMA GEMM + fused argmax -----
// m201-style schedule: 512 thr / 8 waves (2Mx4N), BK=64, 128 KB dbuf LDS via
// global_load_lds dwordx4, counted vmcnt (never 0 mid-loop), XOR bank swizzle
// applied as inverse-swizzled global SOURCE + swizzled ds_read (both-sides),
// setprio(1) around each 16-MFMA cluster.
//
// Staging stagger (half staged only after its last-read barrier):
//   A0(w)@P1(w-1), A1(w)@P2(w-1)  [A halves last read at P3]
//   B0(w)@P3(w-2), B1(w)@P4(w-2)  [B halves last read at P2]
// vmcnt(4) at P4(u) covers through A1(u+1) (4 newer loads = B0,B1(u+2)).

__device__ __forceinline__ void stage_half(const char* g, char* l, int tid)
{
    const int d0 = tid * 16;
    const int d1 = d0 + 8192;
    const int sw = ((d0 >> 7) & 7) << 4;   // same for d1 (row+64 == row mod 8)
    __builtin_amdgcn_global_load_lds(
        (const __attribute__((address_space(1))) void*)(g + (d0 ^ sw)),
        (__attribute__((address_space(3))) void*)(l + d0), 16, 0, 0);
    __builtin_amdgcn_global_load_lds(
        (const __attribute__((address_space(1))) void*)(g + (d1 ^ sw)),
        (__attribute__((address_space(3))) void*)(l + d1), 16, 0, 0);
}

__device__ __forceinline__ const char* tbaseA(const unsigned short* XH, int w, int n0)
{
    const unsigned short* p = (w >= 8) ? (XH + DN) : XH;   // tiles 8..11: A = R
    return (const char*)(p + (size_t)(w & 3) * CH64 + (size_t)n0 * 64);
}
__device__ __forceinline__ const char* tbaseB(const unsigned short* YH, int w, int m0)
{
    const unsigned short* p = (w >= 4 && w < 8) ? (YH + DN) : YH;  // tiles 4..7: B = R
    return (const char*)(p + (size_t)(w & 3) * CH64 + (size_t)m0 * 64);
}

__global__ __launch_bounds__(512, 2) void ksim(
    const unsigned short* __restrict__ XH, const unsigned short* __restrict__ YH,
    float* __restrict__ pmax, int* __restrict__ pidx)
{
    extern __shared__ char smem[];     // 131072 B: buf[2] x (A 32K + B 32K)
    const int tid = threadIdx.x;

    // ---- XCD-aware bijective swizzle: 1296 blocks = 8 XCD x 162 (9x18 region,
    // traversed in 3x3 sub-squares) ----
    const int lid = blockIdx.y * NT + blockIdx.x;
    const int xcd = lid & 7;
    const int r8  = lid >> 3;                 // 0..161
    const int sq  = r8 / 9, wi2 = r8 - sq * 9;
    const int qx  = sq % 3, qy = sq / 3;      // 3x6 grid of 3x3 sub-squares
    const int tx  = (xcd & 3) * 9 + qx * 3 + (wi2 % 3);
    const int ty  = (xcd >> 2) * 18 + qy * 3 + (wi2 / 3);
    const int n0  = tx * 256;                 // X rows
    const int m0  = ty * 256;                 // Y cols

    const int lane = tid & 63, lc = lane & 15, lq = lane >> 4;
    const int wid = tid >> 6, wm = wid >> 2, wn = wid & 3;   // 2M x 4N waves

    // swizzled in-row offset for ds_read_b128 (row stride 128 B)
    const int colk0 = (lq * 16) ^ ((lc & 7) << 4);
    const int abase = wm * 16384 + lc * 128;
    const int bbase = wn * 8192 + lc * 128;

    float4v acc[8][4];
    #pragma unroll
    for (int i = 0; i < 8; ++i)
        #pragma unroll
        for (int j = 0; j < 4; ++j)
            acc[i][j] = (float4v){0.f, 0.f, 0.f, 0.f};

    // ---- prologue: tile0 (A0,A1,B0,B1) + tile1 (B0,B1); A(1) staged in-loop
    {
        const char* a0g = tbaseA(XH, 0, n0);
        const char* b0g = tbaseB(YH, 0, m0);
        const char* b1g = tbaseB(YH, 1, m0);
        stage_half(a0g,          smem,                 tid);
        stage_half(a0g + 16384,  smem + 16384,         tid);
        stage_half(b0g,          smem + 32768,         tid);
        stage_half(b0g + 16384,  smem + 49152,         tid);
        stage_half(b1g,          smem + 65536 + 32768, tid);
        stage_half(b1g + 16384,  smem + 65536 + 49152, tid);
    }
    asm volatile("s_waitcnt vmcnt(4)" ::: "memory");   // tile0 landed
    __builtin_amdgcn_s_barrier();

    #pragma unroll 1
    for (int u = 0; u < 12; ++u) {
        const int AB = (u & 1) << 16;
        const char* sA = smem + AB;
        const char* sB = smem + AB + 32768;
        half8v a[4][2], b0[2][2], b1[2][2];

        // -------- P1: read A(h=0) + B(v=0); stage A0(u+1); MFMA Q00
        #pragma unroll
        for (int i = 0; i < 4; ++i) {
            a[i][0] = *(const half8v*)(sA + (abase + i * 2048 + colk0));
            a[i][1] = *(const half8v*)(sA + (abase + i * 2048 + (colk0 ^ 64)));
        }
        #pragma unroll
        for (int j = 0; j < 2; ++j) {
            b0[j][0] = *(const half8v*)(sB + (bbase + j * 2048 + colk0));
            b0[j][1] = *(const half8v*)(sB + (bbase + j * 2048 + (colk0 ^ 64)));
        }
        if (u < 11)
            stage_half(tbaseA(XH, u + 1, n0), smem + (((u + 1) & 1) << 16), tid);
        __builtin_amdgcn_s_barrier();
        asm volatile("s_waitcnt lgkmcnt(0)" ::: "memory");
        __builtin_amdgcn_s_setprio(1);
        #pragma unroll
        for (int i = 0; i < 4; ++i)
            #pragma unroll
            for (int j = 0; j < 2; ++j) {
                acc[i][j] = __builtin_amdgcn_mfma_f32_16x16x32_f16(a[i][0], b0[j][0], acc[i][j], 0, 0, 0);
                acc[i][j] = __builtin_amdgcn_mfma_f32_16x16x32_f16(a[i][1], b0[j][1], acc[i][j], 0, 0, 0);
            }
        __builtin_amdgcn_s_setprio(0);
        __builtin_amdgcn_s_barrier();

        // -------- P2: read B(v=1); stage A1(u+1); MFMA Q01
        #pragma unroll
        for (int j = 0; j < 2; ++j) {
            b1[j][0] = *(const half8v*)(sB + (bbase + 4096 + j * 2048 + colk0));
            b1[j][1] = *(const half8v*)(sB + (bbase + 4096 + j * 2048 + (colk0 ^ 64)));
        }
        if (u < 11)
            stage_half(tbaseA(XH, u + 1, n0) + 16384,
                       smem + (((u + 1) & 1) << 16) + 16384, tid);
        __builtin_amdgcn_s_barrier();
        asm volatile("s_waitcnt lgkmcnt(0)" ::: "memory");
        __builtin_amdgcn_s_setprio(1);
        #pragma unroll
        for (int i = 0; i < 4; ++i)
            #pragma unroll
            for (int j = 0; j < 2; ++j) {
                acc[i][2 + j] = __builtin_amdgcn_mfma_f32_16x16x32_f16(a[i][0], b1[j][0], acc[i][2 + j], 0, 0, 0);
                acc[i][2 + j] = __builtin_amdgcn_mfma_f32_16x16x32_f16(a[i][1], b1[j][1], acc[i][2 + j], 0, 0, 0);
            }
        __builtin_amdgcn_s_setprio(0);
        __builtin_amdgcn_s_barrier();

        // -------- P3: read A(h=1); stage B0(u+2); MFMA Q11
        #pragma unroll
        for (int i = 0; i < 4; ++i) {
            a[i][0] = *(const half8v*)(sA + (abase + 8192 + i * 2048 + colk0));
            a[i][1] = *(const half8v*)(sA + (abase + 8192 + i * 2048 + (colk0 ^ 64)));
        }
        if (u < 10)
            stage_half(tbaseB(YH, u + 2, m0), smem + AB + 32768, tid);
        __builtin_amdgcn_s_barrier();
        asm volatile("s_waitcnt lgkmcnt(0)" ::: "memory");
        __builtin_amdgcn_s_setprio(1);
        #pragma unroll
        for (int i = 0; i < 4; ++i)
            #pragma unroll
            for (int j = 0; j < 2; ++j) {
                acc[4 + i][2 + j] = __builtin_amdgcn_mfma_f32_16x16x32_f16(a[i][0], b1[j][0], acc[4 + i][2 + j], 0, 0, 0);
                acc[4 + i][2 + j] = __builtin_amdgcn_mfma_f32_16x16x32_f16(a[i][1], b1[j][1], acc[4 + i][2 + j], 0, 0, 0);
            }
        __builtin_amdgcn_s_setprio(0);
        __builtin_amdgcn_s_barrier();

        // -------- P4: stage B1(u+2); MFMA Q10; counted vmcnt; barrier
        if (u < 10)
            stage_half(tbaseB(YH, u + 2, m0) + 16384, smem + AB + 49152, tid);
        __builtin_amdgcn_s_barrier();
        __builtin_amdgcn_s_setprio(1);
        #pragma unroll
        for (int i = 0; i < 4; ++i)
            #pragma unroll
            for (int j = 0; j < 2; ++j) {
                acc[4 + i][j] = __builtin_amdgcn_mfma_f32_16x16x32_f16(a[i][0], b0[j][0], acc[4 + i][j], 0, 0, 0);
                acc[4 + i][j] = __builtin_amdgcn_mfma_f32_16x16x32_f16(a[i][1], b0[j][1], acc[4 + i][j], 0, 0, 0);
            }
        __builtin_amdgcn_s_setprio(0);
        if (u < 10) asm volatile("s_waitcnt vmcnt(4)" ::: "memory");
        else        asm volatile("s_waitcnt vmcnt(0)" ::: "memory");
        __builtin_amdgcn_s_barrier();
    }

    // ---- epilogue: per-row argmax. C/D map: col=lc, row=lq*4+reg. ----
    float* wv  = (float*)smem;            // [256][4]  (LDS reuse, post-drain)
    int*   wix = (int*)(smem + 4096);     // [256][4]

    const int colbase = m0 + wn * 64 + lc;
    #pragma unroll
    for (int mf = 0; mf < 8; ++mf) {
        float bv[4]; int bc[4];
        #pragma unroll
        for (int rg = 0; rg < 4; ++rg) { bv[rg] = acc[mf][0][rg]; bc[rg] = colbase; }
        #pragma unroll
        for (int nf = 1; nf < 4; ++nf) {      // ascending col: strict > = first-max
            int col = colbase + nf * 16;
            #pragma unroll
            for (int rg = 0; rg < 4; ++rg) {
                float v = acc[mf][nf][rg];
                if (v > bv[rg]) { bv[rg] = v; bc[rg] = col; }
            }
        }
        #pragma unroll
        for (int off = 1; off < 16; off <<= 1) {   // xor<16 stays in row group
            #pragma unroll
            for (int rg = 0; rg < 4; ++rg) {
                float ov = __shfl_xor(bv[rg], off, 64);
                int   oi = __shfl_xor(bc[rg], off, 64);
                if (ov > bv[rg] || (ov == bv[rg] && oi < bc[rg])) { bv[rg] = ov; bc[rg] = oi; }
            }
        }
        if (lc == 0) {
            #pragma unroll
            for (int rg = 0; rg < 4; ++rg) {
                int row = wm * 128 + mf * 16 + lq * 4 + rg;
                wv[row * 4 + wn]  = bv[rg];
                wix[row * 4 + wn] = bc[rg];
            }
        }
    }
    __syncthreads();
    if (tid < 256) {
        float b = wv[tid * 4 + 0]; int bi = wix[tid * 4 + 0];
        #pragma unroll
        for (int q = 1; q < 4; ++q) {    // wn ascending = col ascending; strict >
            float v = wv[tid * 4 + q];
            if (v > b) { b = v; bi = wix[tid * 4 + q]; }
        }
        pmax[(size_t)ty * NP + n0 + tid] = b;
        pidx[(size_t)ty * NP + n0 + tid] = bi;
    }
}

// ---------------- Kernel 3: reduce 36 tile partials -> nn_idx -------------
__global__ __launch_bounds__(256) void kred(
    const float* __restrict__ pmax, const int* __restrict__ pidx,
    int* __restrict__ nn)
{
    __shared__ float cv[4][64];
    __shared__ int   ci[4][64];

    const int t = threadIdx.x;
    const int n = blockIdx.x * 64 + (t & 63);
    const int p = t >> 6;

    float b = -INFINITY;
    int bi = 0x7fffffff;
    #pragma unroll
    for (int c = p * 9; c < p * 9 + 9; ++c) {
        float v = pmax[(size_t)c * NP + n];
        int  id = pidx[(size_t)c * NP + n];
        if (v > b || (v == b && id < bi)) { b = v; bi = id; }
    }
    cv[p][t & 63] = b;
    ci[p][t & 63] = bi;
    __syncthreads();
    if (t < 64) {
        b = cv[0][t]; bi = ci[0][t];
        #pragma unroll
        for (int q = 1; q < 4; ++q) {
            float v = cv[q][t]; int id = ci[q][t];
            if (v > b || (v == b && id < bi)) { b = v; bi = id; }
        }
        nn[blockIdx.x * 64 + t] = bi;
    }
}

// ---------------- Kernel 4: gather Y_sel + fused MSE loss ----------------
// y = (H + R) * 2^-8 (H/R at natural scale; error ~2^-25 relative).
__global__ __launch_bounds__(256) void kgather(
    const unsigned short* __restrict__ YH,
    const int* __restrict__ nn,
    const float* __restrict__ Xf, float* __restrict__ Ysel,
    float* __restrict__ lacc)
{
    __shared__ float tile[64][65];
    __shared__ int   idxs[64];
    __shared__ float wsum[4];

    const unsigned short* YR = YH + DN;
    const int n0 = blockIdx.x * 64;
    const int d0 = blockIdx.y * 64;
    const int tid = threadIdx.x;

    if (tid < 64) idxs[tid] = nn[n0 + tid];
    __syncthreads();

    const int c  = tid & 63;
    const int r0 = tid >> 6;

    #pragma unroll
    for (int s = 0; s < 16; ++s) {
        int r = s * 4 + r0;
        int d = d0 + c;
        size_t off = (size_t)(d >> 6) * CH64 + (size_t)idxs[r] * 64 + (d & 63);
        tile[r][c] = (h2f(YH[off]) + h2f(YR[off])) * (1.0f / 256.0f);
    }
    __syncthreads();

    float lsum = 0.0f;
    #pragma unroll
    for (int s = 0; s < 16; ++s) {
        int a = s * 4 + r0;
        int d = d0 + a;
        int n = n0 + c;
        float y = tile[c][a];          // stride-65: conflict-free
        float x = Xf[(size_t)d * NP + n];
        float diff = x - y;
        lsum = fmaf(diff, diff, lsum);
        Ysel[(size_t)d * NP + n] = y;  // coalesced over n
    }

    #pragma unroll
    for (int off = 32; off >= 1; off >>= 1)
        lsum += __shfl_xor(lsum, off, 64);
    if ((tid & 63) == 0) wsum[tid >> 6] = lsum;
    __syncthreads();
    if (tid == 0)
        atomicAdd(lacc, wsum[0] + wsum[1] + wsum[2] + wsum[3]);
}

// ---------------- Kernel 5: finalize loss ----------------
__global__ void kfin(const float* __restrict__ lacc, float* __restrict__ out)
{
    out[0] = lacc[0] * (1.0f / (float)DN);
}

extern "C" void kernel_launch(void* const* d_in, const int* in_sizes, int n_in,
                              void* d_out, int out_size, void* d_ws, size_t ws_size,
                              hipStream_t stream)
{
    const float* X = (const float*)d_in[0];   // X_features [1,256,96,96]
    const float* Y = (const float*)d_in[1];   // Y_features [1,256,96,96]
    // d_in[2], d_in[3] (images) are dead code in the reference — unused.

    float* out = (float*)d_out;
    float* Ysel_out = out + 1;          // output 1: Y_sel [1,D,N]
    float* Xf_out   = out + 1 + DN;     // output 2: Xf   [1,D,N]  (exact fp32)

    // Workspace (~21.6 MB): XH|XR|YH|YR contiguous (ksim derives R = H + DN)
    unsigned short* XH = (unsigned short*)d_ws;
    unsigned short* XR = XH + DN;
    unsigned short* YH = XR + DN;
    unsigned short* YR = YH + DN;
    float* pmax = (float*)(YR + DN);                // NT*NP
    int*   pidx = (int*)(pmax + (size_t)NT * NP);   // NT*NP
    int*   nn   = pidx + (size_t)NT * NP;           // NP
    float* lacc = (float*)(nn + NP);                // 1

    static bool attr_done = false;
    if (!attr_done) {
        hipFuncSetAttribute(reinterpret_cast<const void*>(ksim),
                            hipFuncAttributeMaxDynamicSharedMemorySize, 131072);
        attr_done = true;
    }

    hipLaunchKernelGGL(kprep, dim3(NP / 64, 2), dim3(256), 0, stream,
                       X, Y, Xf_out, XH, XR, YH, YR, lacc);
    hipLaunchKernelGGL(ksim, dim3(NT, NT), dim3(512), 131072, stream,
                       XH, YH, pmax, pidx);
    hipLaunchKernelGGL(kred, dim3(NP / 64), dim3(256), 0, stream,
                       pmax, pidx, nn);
    hipLaunchKernelGGL(kgather, dim3(NP / 64, DC / 64), dim3(256), 0, stream,
                       YH, nn, Xf_out, Ysel_out, lacc);
    hipLaunchKernelGGL(kfin, dim3(1), dim3(1), 0, stream, lacc, out);
}

// Round 2
// 264.157 us; speedup vs baseline: 1.1435x; 1.1435x over previous
//
#include <hip/hip_runtime.h>
#include <math.h>

// Problem constants (B=1 fixed by reference)
#define NP 9216          // S*S spatial positions
#define DC 256           // channels
#define DN (DC * NP)
#define NT 72            // 9216 / 128 tiles per dim
#define KCH (NP * 32)    // halves per k-chunk section of a plane

#define FEPS 2.220446049250313e-16f

typedef __attribute__((ext_vector_type(8))) _Float16 half8v;
typedef __attribute__((ext_vector_type(4))) float   float4v;

union HU { _Float16 h; unsigned short u; };
__device__ __forceinline__ unsigned short f2h(float f) { HU x; x.h = (_Float16)f; return x.u; }
__device__ __forceinline__ float h2f(unsigned short s) { HU x; x.u = s; return (float)x.h; }

// Plane layout (k-major): half index off(n,k) = (k>>5)*KCH + n*32 + (k&31)
// -> one MFMA fragment load (16 positions x 8 halves) is 1KB contiguous,
// perfectly coalesced global_load_dwordx4. ksim runs with no LDS staging
// and no barriers in the K-loop.
//
// Split (SAME scale for both planes): s' = v*inv*2^8;
//   H = fp16(s'),  R = fp16(s' - H)   (exact residual, natural relative scale)
// Then  s'x.s'y = Hx.Hy + Hx.Ry + Rx.Hy  (+ Rx.Ry, dropped: ~2^-22 rel)
// -> THREE CHAINED MFMAs per acc, zero VALU fixup (R1's algebra on R0's
// proven barrier-free schedule).

// ---------------- Kernel 1: fused normalize + fp16 H/R split ----------------
__global__ __launch_bounds__(256) void kprep(
    const float* __restrict__ X, const float* __restrict__ Y,
    float* __restrict__ Xf_out,
    unsigned short* __restrict__ XH, unsigned short* __restrict__ XR,
    unsigned short* __restrict__ YH, unsigned short* __restrict__ YR,
    float* __restrict__ lacc)
{
    __shared__ float tile[64 * 257];   // (n, d) at n*257+d
    __shared__ float psum[4][64];
    __shared__ float invs[64];

    const int t = threadIdx.x;
    const bool isX = (blockIdx.y == 0);
    const float* src = isX ? X : Y;
    unsigned* hT = (unsigned*)(isX ? XH : YH);
    unsigned* rT = (unsigned*)(isX ? XR : YR);
    const int n0 = blockIdx.x * 64;

    if (blockIdx.x == 0 && blockIdx.y == 0 && t == 0) *lacc = 0.0f;

    const int lane = t & 63;
    const int w    = t >> 6;      // wave id -> owns d-range [w*64, w*64+64)

    #pragma unroll 8
    for (int i = 0; i < 64; ++i) {
        int d = w * 64 + i;
        tile[lane * 257 + d] = src[(size_t)d * NP + n0 + lane];
    }
    float s = 0.0f;
    #pragma unroll 8
    for (int i = 0; i < 64; ++i) {
        float v = tile[lane * 257 + w * 64 + i];
        s = fmaf(v, v, s);
    }
    psum[w][lane] = s;
    __syncthreads();
    if (t < 64) {
        float tot = psum[0][t] + psum[1][t] + psum[2][t] + psum[3][t];
        invs[t] = 1.0f / (sqrtf(tot) + FEPS);
    }
    __syncthreads();

    // plane writes, k-major layout; coalesced uints.
    for (int kt = 0; kt < 8; ++kt) {
        #pragma unroll
        for (int p = 0; p < 4; ++p) {
            int idx = p * 256 + t;
            int n = idx >> 4;          // 0..63
            int u = idx & 15;          // uint within chunk (2 halves)
            float inv = invs[n] * 256.0f;
            int d = kt * 32 + 2 * u;
            float s0 = tile[n * 257 + d] * inv;
            float s1 = tile[n * 257 + d + 1] * inv;
            unsigned short h0 = f2h(s0), h1 = f2h(s1);
            unsigned short r0 = f2h(s0 - h2f(h0));
            unsigned short r1 = f2h(s1 - h2f(h1));
            size_t uo = (size_t)kt * (NP * 16) + (size_t)(n0 + n) * 16 + u;
            hT[uo] = (unsigned)h0 | ((unsigned)h1 << 16);
            rT[uo] = (unsigned)r0 | ((unsigned)r1 << 16);
        }
    }

    // exact fp32 Xf output ([d][n], coalesced over n)
    if (isX) {
        const float inv = invs[lane];
        #pragma unroll 8
        for (int i = 0; i < 64; ++i) {
            int d = w * 64 + i;
            Xf_out[(size_t)d * NP + n0 + lane] = tile[lane * 257 + d] * inv;
        }
    }
}

// ---------------- Kernel 2: MFMA sim-GEMM + fused per-row argmax ----------
// Barrier-free K-loop, fragments direct from global (k-major layout),
// compiler-scheduled (R9: hand-pipelining loses to occupancy -> buy MORE
// occupancy: launch_bounds (256,4) = 4 blocks/CU, VGPR<=128 cap is ample).
// XCD-aware locality swizzle as in R0 (concurrent blocks per XCD sit in a
// small patch whose A/B rows fit the 4 MB per-XCD L2).
// sim*2^16 = Hx.Hy + Hx.Ry + Rx.Hy  -- three chained MFMAs, NO VALU fixup.
__global__ __launch_bounds__(256, 4) void ksim(
    const unsigned short* __restrict__ XH, const unsigned short* __restrict__ XR,
    const unsigned short* __restrict__ YH, const unsigned short* __restrict__ YR,
    float* __restrict__ pmax, int* __restrict__ pidx)
{
    __shared__ float v2s[256];
    __shared__ int   i2s[256];

    const int t = threadIdx.x;

    // ---- block swizzle: lid -> (tx,ty) tile coords ----
    const int lid = blockIdx.y * NT + blockIdx.x;
    const int xcd = lid & 7;
    const int r   = lid >> 3;              // 0..647 within region
    const int sq  = r / 36;                // 6x6 sub-square index (0..17)
    const int wi  = r - sq * 36;           // 0..35 within sub-square
    const int qx  = sq % 3, qy = sq / 3;   // 3x6 grid of sub-squares
    const int sx  = wi % 6,  sy = wi / 6;
    const int tx  = (xcd & 3) * 18 + qx * 6 + sx;   // 0..71
    const int ty  = (xcd >> 2) * 36 + qy * 6 + sy;  // 0..71

    const int n0 = tx * 128;
    const int m0 = ty * 128;

    const int L   = t & 63;
    const int wid = t >> 6;
    const int wnb = (wid >> 1) * 64;   // wave n-offset
    const int wmb = (wid & 1) * 64;    // wave m-offset (col half)
    const int lc  = L & 15;
    const int lq  = L >> 4;

    // fragment base pointers (halves); rb/cb via inst offsets (<=13-bit imm)
    const unsigned short* pAh = XH + (size_t)(n0 + wnb + lc) * 32 + lq * 8;
    const unsigned short* pAr = XR + (size_t)(n0 + wnb + lc) * 32 + lq * 8;
    const unsigned short* pBh = YH + (size_t)(m0 + wmb + lc) * 32 + lq * 8;
    const unsigned short* pBr = YR + (size_t)(m0 + wmb + lc) * 32 + lq * 8;

    float4v acc[4][4];
    #pragma unroll
    for (int i = 0; i < 4; ++i)
        #pragma unroll
        for (int j = 0; j < 4; ++j)
            acc[i][j] = (float4v){0.f, 0.f, 0.f, 0.f};

    #pragma unroll 1
    for (int kt = 0; kt < 8; ++kt) {
        half8v Ah[4], Ar[4], Bh[4], Br[4];
        #pragma unroll
        for (int i = 0; i < 4; ++i) {
            Ah[i] = *(const half8v*)(pAh + i * 512);
            Ar[i] = *(const half8v*)(pAr + i * 512);
            Bh[i] = *(const half8v*)(pBh + i * 512);
            Br[i] = *(const half8v*)(pBr + i * 512);
        }
        #pragma unroll
        for (int cb = 0; cb < 4; ++cb)
            #pragma unroll
            for (int rb = 0; rb < 4; ++rb) {
                float4v v = acc[rb][cb];
                v = __builtin_amdgcn_mfma_f32_16x16x32_f16(Ah[rb], Bh[cb], v, 0, 0, 0);
                v = __builtin_amdgcn_mfma_f32_16x16x32_f16(Ah[rb], Br[cb], v, 0, 0, 0);
                v = __builtin_amdgcn_mfma_f32_16x16x32_f16(Ar[rb], Bh[cb], v, 0, 0, 0);
                acc[rb][cb] = v;
            }
        pAh += KCH; pAr += KCH; pBh += KCH; pBr += KCH;
    }

    // ---- epilogue: per-row argmax over own col-half ----
    // C/D map: col=lane&15, row=lq*4+reg. Scale 2^16 is argmax-invariant.
    float bv[16]; int bc[16];
    #pragma unroll
    for (int s = 0; s < 16; ++s) { bv[s] = -INFINITY; bc[s] = 0; }

    #pragma unroll
    for (int rb = 0; rb < 4; ++rb)
        #pragma unroll
        for (int cb = 0; cb < 4; ++cb) {   // cb ascending = col ascending
            const int col = m0 + wmb + cb * 16 + lc;
            #pragma unroll
            for (int r2 = 0; r2 < 4; ++r2) {
                float v = acc[rb][cb][r2];
                int s = rb * 4 + r2;
                if (v > bv[s]) { bv[s] = v; bc[s] = col; }
            }
        }

    // reduce across the 16 lc lanes (xor<16 stays in the quad-group)
    #pragma unroll
    for (int off = 1; off < 16; off <<= 1) {
        #pragma unroll
        for (int s = 0; s < 16; ++s) {
            float ov = __shfl_xor(bv[s], off, 64);
            int   oi = __shfl_xor(bc[s], off, 64);
            if (ov > bv[s] || (ov == bv[s] && oi < bc[s])) { bv[s] = ov; bc[s] = oi; }
        }
    }

    // combine the two column-halves via LDS -> one slot per tile.
    // half0 cols < half1 cols: strict '>' keeps half0 on ties (first-max).
    if (lc == 0) {
        const int half = wid & 1;
        #pragma unroll
        for (int rb = 0; rb < 4; ++rb)
            #pragma unroll
            for (int r2 = 0; r2 < 4; ++r2) {
                int rl = wnb + rb * 16 + lq * 4 + r2;
                v2s[half * 128 + rl] = bv[rb * 4 + r2];
                i2s[half * 128 + rl] = bc[rb * 4 + r2];
            }
    }
    __syncthreads();
    if (t < 128) {
        float va = v2s[t], vb = v2s[128 + t];
        int   ia = i2s[t], ib = i2s[128 + t];
        bool useB = vb > va;
        pmax[(size_t)ty * NP + n0 + t] = useB ? vb : va;
        pidx[(size_t)ty * NP + n0 + t] = useB ? ib : ia;
    }
}

// ---------------- Kernel 3: reduce 72 tile partials -> nn_idx -------------
__global__ __launch_bounds__(256) void kred(
    const float* __restrict__ pmax, const int* __restrict__ pidx,
    int* __restrict__ nn)
{
    __shared__ float cv[4][64];
    __shared__ int   ci[4][64];

    const int t = threadIdx.x;
    const int n = blockIdx.x * 64 + (t & 63);
    const int p = t >> 6;

    float b = -INFINITY;
    int bi = 0x7fffffff;
    #pragma unroll 6
    for (int c = p * 18; c < p * 18 + 18; ++c) {
        float v = pmax[(size_t)c * NP + n];
        int  id = pidx[(size_t)c * NP + n];
        if (v > b || (v == b && id < bi)) { b = v; bi = id; }
    }
    cv[p][t & 63] = b;
    ci[p][t & 63] = bi;
    __syncthreads();
    if (t < 64) {
        b = cv[0][t]; bi = ci[0][t];
        #pragma unroll
        for (int q = 1; q < 4; ++q) {
            float v = cv[q][t]; int id = ci[q][t];
            if (v > b || (v == b && id < bi)) { b = v; bi = id; }
        }
        nn[blockIdx.x * 64 + t] = bi;
    }
}

// ---------------- Kernel 4: gather Y_sel + fused MSE loss ----------------
// y = (H + R) * 2^-8 (H/R same scale; error ~2^-22 relative).
__global__ __launch_bounds__(256) void kgather(
    const unsigned short* __restrict__ YH, const unsigned short* __restrict__ YR,
    const int* __restrict__ nn,
    const float* __restrict__ Xf, float* __restrict__ Ysel,
    float* __restrict__ lacc)
{
    __shared__ float tile[64][65];
    __shared__ int   idxs[64];
    __shared__ float wsum[4];

    const int n0 = blockIdx.x * 64;
    const int d0 = blockIdx.y * 64;
    const int tid = threadIdx.x;

    if (tid < 64) idxs[tid] = nn[n0 + tid];
    __syncthreads();

    const int c  = tid & 63;
    const int r0 = tid >> 6;

    #pragma unroll
    for (int s = 0; s < 16; ++s) {
        int r = s * 4 + r0;
        int d = d0 + c;
        size_t off = (size_t)(d >> 5) * KCH + (size_t)idxs[r] * 32 + (d & 31);
        tile[r][c] = (h2f(YH[off]) + h2f(YR[off])) * (1.0f / 256.0f);
    }
    __syncthreads();

    float lsum = 0.0f;
    #pragma unroll
    for (int s = 0; s < 16; ++s) {
        int a = s * 4 + r0;
        int d = d0 + a;
        int n = n0 + c;
        float y = tile[c][a];          // stride-65: conflict-free
        float x = Xf[(size_t)d * NP + n];
        float diff = x - y;
        lsum = fmaf(diff, diff, lsum);
        Ysel[(size_t)d * NP + n] = y;  // coalesced over n
    }

    #pragma unroll
    for (int off = 32; off >= 1; off >>= 1)
        lsum += __shfl_xor(lsum, off, 64);
    if ((tid & 63) == 0) wsum[tid >> 6] = lsum;
    __syncthreads();
    if (tid == 0)
        atomicAdd(lacc, wsum[0] + wsum[1] + wsum[2] + wsum[3]);
}

// ---------------- Kernel 5: finalize loss ----------------
__global__ void kfin(const float* __restrict__ lacc, float* __restrict__ out)
{
    out[0] = lacc[0] * (1.0f / (float)DN);
}

extern "C" void kernel_launch(void* const* d_in, const int* in_sizes, int n_in,
                              void* d_out, int out_size, void* d_ws, size_t ws_size,
                              hipStream_t stream)
{
    const float* X = (const float*)d_in[0];   // X_features [1,256,96,96]
    const float* Y = (const float*)d_in[1];   // Y_features [1,256,96,96]
    // d_in[2], d_in[3] (images) are dead code in the reference — unused.

    float* out = (float*)d_out;
    float* Ysel_out = out + 1;          // output 1: Y_sel [1,D,N]
    float* Xf_out   = out + 1 + DN;     // output 2: Xf   [1,D,N]  (exact fp32)

    // Workspace (~24.3 MB)
    unsigned short* XH = (unsigned short*)d_ws;   // DN halves each
    unsigned short* XR = XH + DN;
    unsigned short* YH = XR + DN;
    unsigned short* YR = YH + DN;
    float* pmax = (float*)(YR + DN);                // NT*NP
    int*   pidx = (int*)(pmax + (size_t)NT * NP);   // NT*NP
    int*   nn   = pidx + (size_t)NT * NP;           // NP
    float* lacc = (float*)(nn + NP);                // 1

    hipLaunchKernelGGL(kprep, dim3(NP / 64, 2), dim3(256), 0, stream,
                       X, Y, Xf_out, XH, XR, YH, YR, lacc);
    hipLaunchKernelGGL(ksim, dim3(NT, NT), dim3(256), 0, stream,
                       XH, XR, YH, YR, pmax, pidx);
    hipLaunchKernelGGL(kred, dim3(NP / 64), dim3(256), 0, stream,
                       pmax, pidx, nn);
    hipLaunchKernelGGL(kgather, dim3(NP / 64, DC / 64), dim3(256), 0, stream,
                       YH, YR, nn, Xf_out, Ysel_out, lacc);
    hipLaunchKernelGGL(kfin, dim3(1), dim3(1), 0, stream, lacc, out);
}